// Round 20
// baseline (745.525 us; speedup 1.0000x reference)
//
#include <hip/hip_runtime.h>
#include <math.h>

// Problem constants (fixed by the reference setup_inputs)
#define BATCH 32
#define CH    192
#define TFEAT 2048
#define TTXT  512
#define NEGINF (-1e9f)

#define ATTN_ELEMS ((size_t)BATCH * TFEAT * TTXT)   // 33,554,432
#define DUR_OFF    ATTN_ELEMS
#define NEG_OFF    (ATTN_ELEMS + (size_t)BATCH * TTXT)

typedef short bf16x8 __attribute__((ext_vector_type(8)));   // 8 bf16 = 4 VGPR
typedef float f32x16 __attribute__((ext_vector_type(16)));  // 32x32 acc

__device__ __forceinline__ void gload_lds16h(const unsigned short* g,
                                             unsigned short* l) {
  __builtin_amdgcn_global_load_lds(
      (const __attribute__((address_space(1))) void*)g,
      (__attribute__((address_space(3))) void*)l, 16, 0, 0);
}

#define VMCNT(n) asm volatile("s_waitcnt vmcnt(" #n ")" ::: "memory")

__device__ __forceinline__ unsigned short f2b16(float f) {   // RNE bf16
  unsigned u = __float_as_uint(f);
  return (unsigned short)((u + 0x7FFFu + ((u >> 16) & 1u)) >> 16);
}

// ---------------------------------------------------------------------------
// Kernel TA: At2 = fragment-ready bf16 of A = [z | z^2] (M=2048, K=384).
// ---------------------------------------------------------------------------
__global__ __launch_bounds__(256)
void k_transA(const float* __restrict__ z_p, unsigned short* __restrict__ At2) {
  __shared__ float zt[CH][33];
  int b = blockIdx.x >> 6, tblk = blockIdx.x & 63;
  int tid = threadIdx.x;
  int t0 = tblk * 32;
  for (int i = tid; i < CH * 32; i += 256) {
    int c = i >> 5, m = i & 31;
    zt[c][m] = z_p[((size_t)b * CH + c) * TFEAT + t0 + m];
  }
  __syncthreads();
  unsigned short* out = At2 + (size_t)(b * 64 + tblk) * 24 * 512;
  for (int o = tid; o < 24 * 512; o += 256) {
    int kq = o >> 9, rem = o & 511;
    int lane = rem >> 3, j = rem & 7;
    int m = lane & 31, kh = lane >> 5;
    int k = kq * 16 + kh * 8 + j;
    float f;
    if (k < CH) f = zt[k][m];
    else { float z = zt[k - CH][m]; f = z * z; }
    out[o] = f2b16(f);
  }
}

// ---------------------------------------------------------------------------
// Kernel TB: Bt2 = fragment-ready bf16 of B = [W1 ; W2] (K=384, N=512).
// ---------------------------------------------------------------------------
__global__ __launch_bounds__(256)
void k_transB(const float* __restrict__ m_p, const float* __restrict__ logs_p,
              unsigned short* __restrict__ Bt2) {
  __shared__ float w1t[CH][33];
  __shared__ float w2t[CH][33];
  int b = blockIdx.x >> 4, sblk = blockIdx.x & 15;
  int tid = threadIdx.x;
  int s0 = sblk * 32;
  for (int i = tid; i < CH * 32; i += 256) {
    int c = i >> 5, n = i & 31;
    size_t idx = ((size_t)b * CH + c) * TTXT + s0 + n;
    float m = m_p[idx];
    float r = __expf(-2.0f * logs_p[idx]);
    w1t[c][n] = m * r;
    w2t[c][n] = -0.5f * r;
  }
  __syncthreads();
  unsigned short* out = Bt2 + (size_t)(b * 16 + sblk) * 24 * 512;
  for (int o = tid; o < 24 * 512; o += 256) {
    int kq = o >> 9, rem = o & 511;
    int lane = rem >> 3, j = rem & 7;
    int n = lane & 31, kh = lane >> 5;
    int k = kq * 16 + kh * 8 + j;
    float f = (k < CH) ? w1t[k][n] : w2t[k - CH][n];
    out[o] = f2b16(f);
  }
}

// ---------------------------------------------------------------------------
// Kernel A: cadd[b][s] = sum_c(-0.5*log(2pi) - logs) + sum_c(-0.5*m^2*r)
// ---------------------------------------------------------------------------
__global__ void k_cadd(const float* __restrict__ m_p,
                       const float* __restrict__ logs_p,
                       float* __restrict__ cadd) {
  int gid = blockIdx.x * 256 + threadIdx.x;        // 0 .. 16383
  int b = gid >> 9, s = gid & (TTXT - 1);
  const float* mp = m_p    + (size_t)b * CH * TTXT + s;
  const float* lp = logs_p + (size_t)b * CH * TTXT + s;
  float acc = -0.5f * 1.8378770664093453f * (float)CH;   // -C/2 * log(2*pi)
  #pragma unroll 4
  for (int c = 0; c < CH; ++c) {
    float l = lp[(size_t)c * TTXT];
    float m = mp[(size_t)c * TTXT];
    float r = __expf(-2.0f * l);
    acc -= l + 0.5f * m * m * r;
  }
  cadd[gid] = acc;
}

// ---------------------------------------------------------------------------
// Kernel B: bf16 MFMA GEMM (R19, UNCHANGED — dropped out of top-5).
// ---------------------------------------------------------------------------
__global__ __launch_bounds__(512)
void k_mf(const unsigned short* __restrict__ At2,
          const unsigned short* __restrict__ Bt2,
          const float* __restrict__ cadd,
          float* __restrict__ neg,
          unsigned short* __restrict__ negh) {
  int blk = (blockIdx.x & 7) * 128 + (blockIdx.x >> 3);
  int sb = blk & 1;            // 512/256 = 2 col-blocks
  int tb = (blk >> 1) & 15;    // 2048/128 = 16 row-blocks
  int b  = blk >> 5;
  int tid = threadIdx.x, lane = tid & 63, w = tid >> 6;
  int rg = w >> 2, cg = w & 3;
  int trow0 = tb * 128 + rg * 64;
  int scol0 = sb * 256 + cg * 64;

  const unsigned short* ap0 = At2 + ((size_t)(b * 64 + (trow0 >> 5)) * 24) * 512 + lane * 8;
  const unsigned short* ap1 = ap0 + (size_t)24 * 512;
  const unsigned short* bp0 = Bt2 + ((size_t)(b * 16 + (scol0 >> 5)) * 24) * 512 + lane * 8;
  const unsigned short* bp1 = bp0 + (size_t)24 * 512;

  f32x16 acc00, acc01, acc10, acc11;
  #pragma unroll
  for (int r = 0; r < 16; ++r) { acc00[r] = 0.f; acc01[r] = 0.f; acc10[r] = 0.f; acc11[r] = 0.f; }

  bf16x8 a0A, a1A, b0A, b1A;
  bf16x8 a0B, a1B, b0B, b1B;

  auto LDA = [&](bf16x8& x0, bf16x8& x1, bf16x8& y0, bf16x8& y1, int kq) {
    x0 = *(const bf16x8*)(ap0 + (size_t)kq * 512);
    x1 = *(const bf16x8*)(ap1 + (size_t)kq * 512);
    y0 = *(const bf16x8*)(bp0 + (size_t)kq * 512);
    y1 = *(const bf16x8*)(bp1 + (size_t)kq * 512);
  };
  auto FMA = [&](bf16x8& x0, bf16x8& x1, bf16x8& y0, bf16x8& y1) {
    acc00 = __builtin_amdgcn_mfma_f32_32x32x16_bf16(x0, y0, acc00, 0, 0, 0);
    acc01 = __builtin_amdgcn_mfma_f32_32x32x16_bf16(x0, y1, acc01, 0, 0, 0);
    acc10 = __builtin_amdgcn_mfma_f32_32x32x16_bf16(x1, y0, acc10, 0, 0, 0);
    acc11 = __builtin_amdgcn_mfma_f32_32x32x16_bf16(x1, y1, acc11, 0, 0, 0);
  };

  LDA(a0A, a1A, b0A, b1A, 0);
  #pragma unroll
  for (int kq = 0; kq < 24; kq += 2) {
    LDA(a0B, a1B, b0B, b1B, kq + 1);
    FMA(a0A, a1A, b0A, b1A);
    __builtin_amdgcn_sched_barrier(0);
    if (kq + 2 < 24) LDA(a0A, a1A, b0A, b1A, kq + 2);
    FMA(a0B, a1B, b0B, b1B);
    __builtin_amdgcn_sched_barrier(0);
  }

  #pragma unroll
  for (int ti = 0; ti < 2; ++ti) {
    #pragma unroll
    for (int tj = 0; tj < 2; ++tj) {
      const f32x16& v = (ti == 0) ? ((tj == 0) ? acc00 : acc01)
                                  : ((tj == 0) ? acc10 : acc11);
      int s = scol0 + tj * 32 + (lane & 31);
      float cv = cadd[b * TTXT + s];
      int tB = trow0 + ti * 32 + 4 * (lane >> 5);
      float* np_ = neg + (size_t)b * TFEAT * TTXT + s;
      #pragma unroll
      for (int r = 0; r < 16; ++r) {
        int t = tB + (r & 3) + 8 * (r >> 2);
        float o = v[r] + cv;
        np_[(size_t)t * TTXT] = o;
        negh[(((size_t)b * 128 + (t >> 4)) * 8 + (s >> 6)) * 1024
             + (t & 15) * 64 + (s & 63)] = f2b16(o);
      }
    }
  }
}

// ---------------------------------------------------------------------------
// Kernel C (R20): skewed-wavefront DP, TWO BATCHES PER BLOCK (1024 thr, 16
// blocks -> 4 waves/SIMD). A/B test of the ~390cy/row residue: if it's
// per-wave serial stall (chain+hazard latency at 2 waves/SIMD), co-resident
// batch B fills batch A's bubbles -> ~2x. Per-wave code verbatim R16/R19.
// LDS: 2 x (ring 64KB + bnd 1.5KB) = 134KB. Two backtrack walkers.
// ---------------------------------------------------------------------------
#define KROWS 16
#define NWIN  (TFEAT / KROWS)     // 128 windows
#define NMASKW (TTXT / KROWS)     // 32 masked windows

__device__ __forceinline__ float dpp_shr1(float v) {
  return __int_as_float(__builtin_amdgcn_update_dpp(
      __float_as_int(v), __float_as_int(v), 0x138 /*wave_shr:1*/, 0xF, 0xF, false));
}

__global__ __launch_bounds__(1024, 1)
void k_dp(const unsigned short* __restrict__ negh, float* __restrict__ dur,
          int* __restrict__ idx_out, const float* __restrict__ x_mask,
          unsigned long long* __restrict__ gbits_all) {
  __shared__ unsigned short ringh[2][8][4][KROWS * 64];  // 131072 B
  __shared__ float bndlds[2][3][8][KROWS];               //   3072 B
  int tid = threadIdx.x;
  int half = tid >> 9;                    // 0/1: which batch of the pair
  int tid9 = tid & 511;
  int lane = tid & 63, w = tid9 >> 6;     // wave-within-batch 0..7
  int b = blockIdx.x * 2 + half;
  const unsigned short* nb =
      negh + (((size_t)b * NWIN) * 8 + w) * 1024 + lane * 8;
  unsigned long long* gbits = gbits_all + (size_t)b * 8 * TFEAT;  // [8][2048]

  if (tid9 < 3 * 8 * KROWS / 4 * 4 && tid9 < 384) ((float*)bndlds[half])[tid9] = NEGINF;

  auto stage = [&](int j) {               // 2 contiguous 1KB loads
    int slot = j & 3;
    const unsigned short* s0 = nb + (size_t)j * 8 * 1024;
    gload_lds16h(s0,       &ringh[half][w][slot][0]);
    gload_lds16h(s0 + 512, &ringh[half][w][slot][512]);
  };

  stage(0); stage(1); stage(2);
  __syncthreads();                        // drains prologue loads + bndlds init

  float prev = NEGINF;
  for (int p = 0; p < NWIN + 8; ++p) {
    int i = p - w;                        // this wave's window this phase
    if (i >= 0 && i + 3 < NWIN) { stage(i + 3); VMCNT(6); }
    else if (i >= 0) {
      int rem = NWIN - 1 - i;
      if (rem == 2)      VMCNT(4);
      else if (rem == 1) VMCNT(2);
      else               VMCNT(0);
    }
    asm volatile("s_waitcnt lgkmcnt(0)" ::: "memory");
    __builtin_amdgcn_s_barrier();         // bndlds(prev phase) visible
    __builtin_amdgcn_sched_barrier(0);

    if (i >= 0 && i < NWIN) {
      // hoisted boundary values (wave-uniform)
      float s_bnd[KROWS];
      if (w > 0) {
        float v   = bndlds[half][i % 3][w - 1][lane & 15];
        float v15 = bndlds[half][(i + 2) % 3][w - 1][15];
        s_bnd[0] = __int_as_float(__builtin_amdgcn_readfirstlane(__float_as_int(v15)));
        #pragma unroll
        for (int r = 1; r < KROWS; ++r)
          s_bnd[r] = __int_as_float(__builtin_amdgcn_readlane(__float_as_int(v), r - 1));
      } else {
        #pragma unroll
        for (int r = 0; r < KROWS; ++r) s_bnd[r] = NEGINF;
        if (i == 0) s_bnd[0] = 0.0f;      // y==0, x==0 edge
      }
      // own-slice nf: bf16 -> f32 exact decode
      float cur[KROWS];
      #pragma unroll
      for (int r = 0; r < KROWS; ++r)
        cur[r] = __uint_as_float((unsigned)ringh[half][w][i & 3][r * 64 + lane] << 16);

      int y0 = i * KROWS;
      bool masked = (i < NMASKW);
      unsigned keep_lo = 0, keep_hi = 0;
      float bkeep = 0.0f;
      unsigned long long andm = (w == 0) ? ~1ull : ~0ull;   // x==0 never moves
      #pragma unroll
      for (int r = 0; r < KROWS; ++r) {
        float upd = dpp_shr1(prev);
        float up = (lane == 0) ? s_bnd[r] : upd;
        bool force = masked && (tid9 == y0 + r);
        bool gt = prev < up;
        unsigned long long m = __ballot(force || gt) & andm;  // wave-uniform
        bool mine = (lane == r);
        keep_lo = mine ? (unsigned)m : keep_lo;
        keep_hi = mine ? (unsigned)(m >> 32) : keep_hi;
        float vc = force ? NEGINF : prev;
        prev = fmaxf(vc, up) + cur[r];
        float v63 = __int_as_float(
            __builtin_amdgcn_readlane(__float_as_int(prev), 63));  // uniform
        bkeep = mine ? v63 : bkeep;
      }
      if (lane < KROWS) {                 // one exec toggle per window
        bndlds[half][i % 3][w][lane] = bkeep;
        gbits[(size_t)w * TFEAT + y0 + lane] =
            ((unsigned long long)keep_hi << 32) | keep_lo;   // 128B contiguous
      }
    }
  }
  VMCNT(0);
  __syncthreads();                        // gbits stores drained + visible

  // ---- serial backtrack: one walker per batch (tid9 == 0 in each half;
  // the two walkers live in different waves -> run in parallel).
  if (tid9 == 0) {
    const float* xm = x_mask + (size_t)b * TTXT;
    int idx = TTXT - 1, cnt = 0;
    unsigned long long ua[16], ub[16]; int qi[16];
    #pragma unroll
    for (int q16 = 0; q16 < 16; ++q16) {  // rows 2032..2047 (slot = y&15)
      ua[q16] = gbits[(size_t)7 * TFEAT + 2032 + q16];
      ub[q16] = gbits[(size_t)6 * TFEAT + 2032 + q16];
      qi[q16] = 7;
    }
    for (int yb = 2032; yb >= 16; yb -= 16) {
      #pragma unroll
      for (int jj = 15; jj >= 0; --jj) {
        int y = yb + jj;                  // slot = jj (yb % 16 == 0)
        unsigned long long w64 = ((idx >> 6) == qi[jj]) ? ua[jj] : ub[jj];
        idx_out[b * TFEAT + y] = idx;
        cnt++;
        if ((w64 >> (idx & 63)) & 1ull) {
          dur[b * TTXT + idx] = (float)cnt * xm[idx];
          cnt = 0; idx--;
        }
        int q = idx >> 6;                 // refill slot jj for row y-16
        int qm = q > 0 ? q - 1 : 0;
        ua[jj] = gbits[(size_t)q  * TFEAT + (y - 16)];
        ub[jj] = gbits[(size_t)qm * TFEAT + (y - 16)];
        qi[jj] = q;
      }
    }
    #pragma unroll
    for (int jj = 15; jj >= 0; --jj) {    // tail rows 15..0
      int y = jj;
      unsigned long long w64 = ((idx >> 6) == qi[jj]) ? ua[jj] : ub[jj];
      idx_out[b * TFEAT + y] = idx;
      cnt++;
      if ((w64 >> (idx & 63)) & 1ull) {
        dur[b * TTXT + idx] = (float)cnt * xm[idx];
        cnt = 0; idx--;
      }
    }
    dur[b * TTXT] = (float)cnt * xm[0];   // idx == 0 tail run
  }
}

// ---------------------------------------------------------------------------
// Kernel D: attn[b,y,x] = (x == idx[y]) * x_mask[b,x] * y_mask[b,y]
// ---------------------------------------------------------------------------
__global__ void k_attn(const int* __restrict__ idx_arr,
                       const float* __restrict__ x_mask,
                       const float* __restrict__ y_mask,
                       float* __restrict__ attn) {
  size_t gid = (size_t)blockIdx.x * 256 + threadIdx.x;
  size_t e = gid << 2;               // 4 floats per thread
  int b = (int)(e >> 20);            // TFEAT*TTXT = 2^20
  int rem = (int)(e & 1048575u);
  int y = rem >> 9;
  int x0 = rem & 511;
  int idx = idx_arr[b * TFEAT + y];
  float4 v = {0.f, 0.f, 0.f, 0.f};
  int d = idx - x0;
  if (d >= 0 && d < 4) {
    ((float*)&v)[d] = x_mask[b * TTXT + idx] * y_mask[b * TFEAT + y];
  }
  *(float4*)(attn + e) = v;
}

// ---------------------------------------------------------------------------
extern "C" void kernel_launch(void* const* d_in, const int* in_sizes, int n_in,
                              void* d_out, int out_size, void* d_ws, size_t ws_size,
                              hipStream_t stream) {
  const float* z_p    = (const float*)d_in[0];
  const float* m_p    = (const float*)d_in[1];
  const float* logs_p = (const float*)d_in[2];
  const float* x_mask = (const float*)d_in[3];
  const float* y_mask = (const float*)d_in[4];

  float* out  = (float*)d_out;
  float* attn = out;
  float* dur  = out + DUR_OFF;
  float* neg  = out + NEG_OFF;

  // scratch in the attn region (134,217,728 B; fully rewritten by k_attn):
  //   gbits 4MB | negh 64MB | At2 48MB | Bt2 12MB  (exact fit)
  char* scr = (char*)attn;
  unsigned long long* gbits = (unsigned long long*)scr;
  unsigned short* negh = (unsigned short*)(scr + 4194304);
  unsigned short* At2  = (unsigned short*)(scr + 71303168);
  unsigned short* Bt2  = (unsigned short*)(scr + 121634816);

  // workspace: cadd (64 KiB) + idx array (256 KiB)
  float* cadd = (float*)d_ws;
  int*   idxa = (int*)((char*)d_ws + 65536);

  k_transA<<<BATCH * 64, 256, 0, stream>>>(z_p, At2);
  k_transB<<<BATCH * 16, 256, 0, stream>>>(m_p, logs_p, Bt2);
  k_cadd<<<(BATCH * TTXT) / 256, 256, 0, stream>>>(m_p, logs_p, cadd);
  k_mf<<<1024, 512, 0, stream>>>(At2, Bt2, cadd, neg, negh);
  k_dp<<<BATCH / 2, 1024, 0, stream>>>(negh, dur, idxa, x_mask, gbits);
  k_attn<<<(int)(ATTN_ELEMS / 4 / 256), 256, 0, stream>>>(idxa, x_mask, y_mask, attn);
}

// Round 21
// 517.014 us; speedup vs baseline: 1.4420x; 1.4420x over previous
//
#include <hip/hip_runtime.h>
#include <math.h>

// Problem constants (fixed by the reference setup_inputs)
#define BATCH 32
#define CH    192
#define TFEAT 2048
#define TTXT  512
#define NEGINF (-1e9f)

#define ATTN_ELEMS ((size_t)BATCH * TFEAT * TTXT)   // 33,554,432
#define DUR_OFF    ATTN_ELEMS
#define NEG_OFF    (ATTN_ELEMS + (size_t)BATCH * TTXT)

typedef short bf16x8 __attribute__((ext_vector_type(8)));   // 8 bf16 = 4 VGPR
typedef float f32x16 __attribute__((ext_vector_type(16)));  // 32x32 acc

__device__ __forceinline__ void gload_lds16h(const unsigned short* g,
                                             unsigned short* l) {
  __builtin_amdgcn_global_load_lds(
      (const __attribute__((address_space(1))) void*)g,
      (__attribute__((address_space(3))) void*)l, 16, 0, 0);
}

#define VMCNT(n) asm volatile("s_waitcnt vmcnt(" #n ")" ::: "memory")

__device__ __forceinline__ unsigned short f2b16(float f) {   // RNE bf16
  unsigned u = __float_as_uint(f);
  return (unsigned short)((u + 0x7FFFu + ((u >> 16) & 1u)) >> 16);
}

// ---------------------------------------------------------------------------
// Kernel TA: At2 = fragment-ready bf16 of A = [z | z^2] (M=2048, K=384).
// ---------------------------------------------------------------------------
__global__ __launch_bounds__(256)
void k_transA(const float* __restrict__ z_p, unsigned short* __restrict__ At2) {
  __shared__ float zt[CH][33];
  int b = blockIdx.x >> 6, tblk = blockIdx.x & 63;
  int tid = threadIdx.x;
  int t0 = tblk * 32;
  for (int i = tid; i < CH * 32; i += 256) {
    int c = i >> 5, m = i & 31;
    zt[c][m] = z_p[((size_t)b * CH + c) * TFEAT + t0 + m];
  }
  __syncthreads();
  unsigned short* out = At2 + (size_t)(b * 64 + tblk) * 24 * 512;
  for (int o = tid; o < 24 * 512; o += 256) {
    int kq = o >> 9, rem = o & 511;
    int lane = rem >> 3, j = rem & 7;
    int m = lane & 31, kh = lane >> 5;
    int k = kq * 16 + kh * 8 + j;
    float f;
    if (k < CH) f = zt[k][m];
    else { float z = zt[k - CH][m]; f = z * z; }
    out[o] = f2b16(f);
  }
}

// ---------------------------------------------------------------------------
// Kernel TB: Bt2 = fragment-ready bf16 of B = [W1 ; W2] (K=384, N=512).
// ---------------------------------------------------------------------------
__global__ __launch_bounds__(256)
void k_transB(const float* __restrict__ m_p, const float* __restrict__ logs_p,
              unsigned short* __restrict__ Bt2) {
  __shared__ float w1t[CH][33];
  __shared__ float w2t[CH][33];
  int b = blockIdx.x >> 4, sblk = blockIdx.x & 15;
  int tid = threadIdx.x;
  int s0 = sblk * 32;
  for (int i = tid; i < CH * 32; i += 256) {
    int c = i >> 5, n = i & 31;
    size_t idx = ((size_t)b * CH + c) * TTXT + s0 + n;
    float m = m_p[idx];
    float r = __expf(-2.0f * logs_p[idx]);
    w1t[c][n] = m * r;
    w2t[c][n] = -0.5f * r;
  }
  __syncthreads();
  unsigned short* out = Bt2 + (size_t)(b * 16 + sblk) * 24 * 512;
  for (int o = tid; o < 24 * 512; o += 256) {
    int kq = o >> 9, rem = o & 511;
    int lane = rem >> 3, j = rem & 7;
    int n = lane & 31, kh = lane >> 5;
    int k = kq * 16 + kh * 8 + j;
    float f = (k < CH) ? w1t[k][n] : w2t[k - CH][n];
    out[o] = f2b16(f);
  }
}

// ---------------------------------------------------------------------------
// Kernel A: cadd[b][s] = sum_c(-0.5*log(2pi) - logs) + sum_c(-0.5*m^2*r)
// ---------------------------------------------------------------------------
__global__ void k_cadd(const float* __restrict__ m_p,
                       const float* __restrict__ logs_p,
                       float* __restrict__ cadd) {
  int gid = blockIdx.x * 256 + threadIdx.x;        // 0 .. 16383
  int b = gid >> 9, s = gid & (TTXT - 1);
  const float* mp = m_p    + (size_t)b * CH * TTXT + s;
  const float* lp = logs_p + (size_t)b * CH * TTXT + s;
  float acc = -0.5f * 1.8378770664093453f * (float)CH;   // -C/2 * log(2*pi)
  #pragma unroll 4
  for (int c = 0; c < CH; ++c) {
    float l = lp[(size_t)c * TTXT];
    float m = mp[(size_t)c * TTXT];
    float r = __expf(-2.0f * l);
    acc -= l + 0.5f * m * m * r;
  }
  cadd[gid] = acc;
}

// ---------------------------------------------------------------------------
// Kernel B: bf16 MFMA GEMM (R19, UNCHANGED).
// ---------------------------------------------------------------------------
__global__ __launch_bounds__(512)
void k_mf(const unsigned short* __restrict__ At2,
          const unsigned short* __restrict__ Bt2,
          const float* __restrict__ cadd,
          float* __restrict__ neg,
          unsigned short* __restrict__ negh) {
  int blk = (blockIdx.x & 7) * 128 + (blockIdx.x >> 3);
  int sb = blk & 1;            // 512/256 = 2 col-blocks
  int tb = (blk >> 1) & 15;    // 2048/128 = 16 row-blocks
  int b  = blk >> 5;
  int tid = threadIdx.x, lane = tid & 63, w = tid >> 6;
  int rg = w >> 2, cg = w & 3;
  int trow0 = tb * 128 + rg * 64;
  int scol0 = sb * 256 + cg * 64;

  const unsigned short* ap0 = At2 + ((size_t)(b * 64 + (trow0 >> 5)) * 24) * 512 + lane * 8;
  const unsigned short* ap1 = ap0 + (size_t)24 * 512;
  const unsigned short* bp0 = Bt2 + ((size_t)(b * 16 + (scol0 >> 5)) * 24) * 512 + lane * 8;
  const unsigned short* bp1 = bp0 + (size_t)24 * 512;

  f32x16 acc00, acc01, acc10, acc11;
  #pragma unroll
  for (int r = 0; r < 16; ++r) { acc00[r] = 0.f; acc01[r] = 0.f; acc10[r] = 0.f; acc11[r] = 0.f; }

  bf16x8 a0A, a1A, b0A, b1A;
  bf16x8 a0B, a1B, b0B, b1B;

  auto LDA = [&](bf16x8& x0, bf16x8& x1, bf16x8& y0, bf16x8& y1, int kq) {
    x0 = *(const bf16x8*)(ap0 + (size_t)kq * 512);
    x1 = *(const bf16x8*)(ap1 + (size_t)kq * 512);
    y0 = *(const bf16x8*)(bp0 + (size_t)kq * 512);
    y1 = *(const bf16x8*)(bp1 + (size_t)kq * 512);
  };
  auto FMA = [&](bf16x8& x0, bf16x8& x1, bf16x8& y0, bf16x8& y1) {
    acc00 = __builtin_amdgcn_mfma_f32_32x32x16_bf16(x0, y0, acc00, 0, 0, 0);
    acc01 = __builtin_amdgcn_mfma_f32_32x32x16_bf16(x0, y1, acc01, 0, 0, 0);
    acc10 = __builtin_amdgcn_mfma_f32_32x32x16_bf16(x1, y0, acc10, 0, 0, 0);
    acc11 = __builtin_amdgcn_mfma_f32_32x32x16_bf16(x1, y1, acc11, 0, 0, 0);
  };

  LDA(a0A, a1A, b0A, b1A, 0);
  #pragma unroll
  for (int kq = 0; kq < 24; kq += 2) {
    LDA(a0B, a1B, b0B, b1B, kq + 1);
    FMA(a0A, a1A, b0A, b1A);
    __builtin_amdgcn_sched_barrier(0);
    if (kq + 2 < 24) LDA(a0A, a1A, b0A, b1A, kq + 2);
    FMA(a0B, a1B, b0B, b1B);
    __builtin_amdgcn_sched_barrier(0);
  }

  #pragma unroll
  for (int ti = 0; ti < 2; ++ti) {
    #pragma unroll
    for (int tj = 0; tj < 2; ++tj) {
      const f32x16& v = (ti == 0) ? ((tj == 0) ? acc00 : acc01)
                                  : ((tj == 0) ? acc10 : acc11);
      int s = scol0 + tj * 32 + (lane & 31);
      float cv = cadd[b * TTXT + s];
      int tB = trow0 + ti * 32 + 4 * (lane >> 5);
      float* np_ = neg + (size_t)b * TFEAT * TTXT + s;
      #pragma unroll
      for (int r = 0; r < 16; ++r) {
        int t = tB + (r & 3) + 8 * (r >> 2);
        float o = v[r] + cv;
        np_[(size_t)t * TTXT] = o;
        negh[(((size_t)b * 128 + (t >> 4)) * 8 + (s >> 6)) * 1024
             + (t & 15) * 64 + (s & 63)] = f2b16(o);
      }
    }
  }
}

// ---------------------------------------------------------------------------
// Kernel C (R21): skewed-wavefront DP = R19 verbatim EXCEPT the vmcnt
// schedule. CDNA vmcnt counts STORES too and retires in order (m135);
// R19's VMCNT(6) therefore waited for the gbits store of window i-3 (HBM
// round-trip) plus window i+1's loads, EVERY phase. Store-aware counts:
// ops issued after window i's loads = 2*min(3, NWIN-1-i) loads
// + min(i,3) stores -> VMCNT(9) steady state, ramp 6/7/8 in, 7/5/3 out.
// (R20's 2-batch shared-barrier coupling regressed 356->583; reverted.)
// ---------------------------------------------------------------------------
#define KROWS 16
#define NWIN  (TFEAT / KROWS)     // 128 windows
#define NMASKW (TTXT / KROWS)     // 32 masked windows

__device__ __forceinline__ float dpp_shr1(float v) {
  return __int_as_float(__builtin_amdgcn_update_dpp(
      __float_as_int(v), __float_as_int(v), 0x138 /*wave_shr:1*/, 0xF, 0xF, false));
}

__global__ __launch_bounds__(512, 1)
void k_dp(const unsigned short* __restrict__ negh, float* __restrict__ dur,
          int* __restrict__ idx_out, const float* __restrict__ x_mask,
          unsigned long long* __restrict__ gbits_all) {
  __shared__ unsigned short ringh[8][4][KROWS * 64];  // 65536 B per-wave ring
  __shared__ float bndlds[3][8][KROWS];               //  1536 B boundary ring
  int b = blockIdx.x, tid = threadIdx.x;
  int lane = tid & 63, w = tid >> 6;
  // wave w's slice stream: blocks of 1024 ushorts per (window, wave)
  const unsigned short* nb =
      negh + (((size_t)b * NWIN) * 8 + w) * 1024 + lane * 8;
  unsigned long long* gbits = gbits_all + (size_t)b * 8 * TFEAT;  // [8][2048]

  if (tid < 3 * 8 * KROWS) ((float*)bndlds)[tid] = NEGINF;

  auto stage = [&](int j) {               // 2 contiguous 1KB loads
    int slot = j & 3;
    const unsigned short* s0 = nb + (size_t)j * 8 * 1024;
    gload_lds16h(s0,       &ringh[w][slot][0]);
    gload_lds16h(s0 + 512, &ringh[w][slot][512]);
  };

  stage(0); stage(1); stage(2);
  __syncthreads();                        // drains prologue loads + bndlds init

  float prev = NEGINF;
  for (int p = 0; p < NWIN + 8; ++p) {
    int i = p - w;                        // this wave's window this phase
    if (i >= 0 && i + 3 < NWIN) {
      stage(i + 3);
      // store-aware wait: window i's loads done without draining newer
      // stores (2*min(3,rem) loads + min(i,3) stores issued after them)
      if (i >= 3)      VMCNT(9);
      else if (i == 2) VMCNT(8);
      else if (i == 1) VMCNT(7);
      else             VMCNT(6);          // i == 0
    } else if (i >= 0) {
      int rem = NWIN - 1 - i;
      if (rem == 2)      VMCNT(7);        // 4 loads + 3 stores
      else if (rem == 1) VMCNT(5);        // 2 loads + 3 stores
      else               VMCNT(3);        // 0 loads + 3 stores
    }
    asm volatile("s_waitcnt lgkmcnt(0)" ::: "memory");
    __builtin_amdgcn_s_barrier();         // bndlds(prev phase) visible
    __builtin_amdgcn_sched_barrier(0);

    if (i >= 0 && i < NWIN) {
      // hoisted boundary values (wave-uniform)
      float s_bnd[KROWS];
      if (w > 0) {
        float v   = bndlds[i % 3][w - 1][lane & 15];
        float v15 = bndlds[(i + 2) % 3][w - 1][15];
        s_bnd[0] = __int_as_float(__builtin_amdgcn_readfirstlane(__float_as_int(v15)));
        #pragma unroll
        for (int r = 1; r < KROWS; ++r)
          s_bnd[r] = __int_as_float(__builtin_amdgcn_readlane(__float_as_int(v), r - 1));
      } else {
        #pragma unroll
        for (int r = 0; r < KROWS; ++r) s_bnd[r] = NEGINF;
        if (i == 0) s_bnd[0] = 0.0f;      // y==0, x==0 edge
      }
      // own-slice nf: bf16 -> f32 exact decode
      float cur[KROWS];
      #pragma unroll
      for (int r = 0; r < KROWS; ++r)
        cur[r] = __uint_as_float((unsigned)ringh[w][i & 3][r * 64 + lane] << 16);

      int y0 = i * KROWS;
      bool masked = (i < NMASKW);
      unsigned keep_lo = 0, keep_hi = 0;
      float bkeep = 0.0f;
      unsigned long long andm = (w == 0) ? ~1ull : ~0ull;   // x==0 never moves
      #pragma unroll
      for (int r = 0; r < KROWS; ++r) {
        float upd = dpp_shr1(prev);
        float up = (lane == 0) ? s_bnd[r] : upd;
        bool force = masked && (tid == y0 + r);
        bool gt = prev < up;
        unsigned long long m = __ballot(force || gt) & andm;  // uniform
        bool mine = (lane == r);
        keep_lo = mine ? (unsigned)m : keep_lo;
        keep_hi = mine ? (unsigned)(m >> 32) : keep_hi;
        float vc = force ? NEGINF : prev;
        prev = fmaxf(vc, up) + cur[r];
        float v63 = __int_as_float(
            __builtin_amdgcn_readlane(__float_as_int(prev), 63));  // uniform
        bkeep = mine ? v63 : bkeep;
      }
      if (lane < KROWS) {                 // one exec toggle per window
        bndlds[i % 3][w][lane] = bkeep;
        gbits[(size_t)w * TFEAT + y0 + lane] =
            ((unsigned long long)keep_hi << 32) | keep_lo;   // 128B contiguous
      }
    }
  }
  VMCNT(0);
  __syncthreads();                        // gbits stores drained + visible

  // ---- serial backtrack (tid 0), 16-deep register ring over global bits.
  if (tid == 0) {
    const float* xm = x_mask + (size_t)b * TTXT;
    int idx = TTXT - 1, cnt = 0;
    unsigned long long ua[16], ub[16]; int qi[16];
    #pragma unroll
    for (int q16 = 0; q16 < 16; ++q16) {  // rows 2032..2047 (slot = y&15)
      ua[q16] = gbits[(size_t)7 * TFEAT + 2032 + q16];
      ub[q16] = gbits[(size_t)6 * TFEAT + 2032 + q16];
      qi[q16] = 7;
    }
    for (int yb = 2032; yb >= 16; yb -= 16) {
      #pragma unroll
      for (int jj = 15; jj >= 0; --jj) {
        int y = yb + jj;                  // slot = jj (yb % 16 == 0)
        unsigned long long w64 = ((idx >> 6) == qi[jj]) ? ua[jj] : ub[jj];
        idx_out[b * TFEAT + y] = idx;
        cnt++;
        if ((w64 >> (idx & 63)) & 1ull) {
          dur[b * TTXT + idx] = (float)cnt * xm[idx];
          cnt = 0; idx--;
        }
        int q = idx >> 6;                 // refill slot jj for row y-16
        int qm = q > 0 ? q - 1 : 0;
        ua[jj] = gbits[(size_t)q  * TFEAT + (y - 16)];
        ub[jj] = gbits[(size_t)qm * TFEAT + (y - 16)];
        qi[jj] = q;
      }
    }
    #pragma unroll
    for (int jj = 15; jj >= 0; --jj) {    // tail rows 15..0
      int y = jj;
      unsigned long long w64 = ((idx >> 6) == qi[jj]) ? ua[jj] : ub[jj];
      idx_out[b * TFEAT + y] = idx;
      cnt++;
      if ((w64 >> (idx & 63)) & 1ull) {
        dur[b * TTXT + idx] = (float)cnt * xm[idx];
        cnt = 0; idx--;
      }
    }
    dur[b * TTXT] = (float)cnt * xm[0];   // idx == 0 tail run
  }
}

// ---------------------------------------------------------------------------
// Kernel D: attn[b,y,x] = (x == idx[y]) * x_mask[b,x] * y_mask[b,y]
// ---------------------------------------------------------------------------
__global__ void k_attn(const int* __restrict__ idx_arr,
                       const float* __restrict__ x_mask,
                       const float* __restrict__ y_mask,
                       float* __restrict__ attn) {
  size_t gid = (size_t)blockIdx.x * 256 + threadIdx.x;
  size_t e = gid << 2;               // 4 floats per thread
  int b = (int)(e >> 20);            // TFEAT*TTXT = 2^20
  int rem = (int)(e & 1048575u);
  int y = rem >> 9;
  int x0 = rem & 511;
  int idx = idx_arr[b * TFEAT + y];
  float4 v = {0.f, 0.f, 0.f, 0.f};
  int d = idx - x0;
  if (d >= 0 && d < 4) {
    ((float*)&v)[d] = x_mask[b * TTXT + idx] * y_mask[b * TFEAT + y];
  }
  *(float4*)(attn + e) = v;
}

// ---------------------------------------------------------------------------
extern "C" void kernel_launch(void* const* d_in, const int* in_sizes, int n_in,
                              void* d_out, int out_size, void* d_ws, size_t ws_size,
                              hipStream_t stream) {
  const float* z_p    = (const float*)d_in[0];
  const float* m_p    = (const float*)d_in[1];
  const float* logs_p = (const float*)d_in[2];
  const float* x_mask = (const float*)d_in[3];
  const float* y_mask = (const float*)d_in[4];

  float* out  = (float*)d_out;
  float* attn = out;
  float* dur  = out + DUR_OFF;
  float* neg  = out + NEG_OFF;

  // scratch in the attn region (134,217,728 B; fully rewritten by k_attn):
  //   gbits 4MB | negh 64MB | At2 48MB | Bt2 12MB  (exact fit)
  char* scr = (char*)attn;
  unsigned long long* gbits = (unsigned long long*)scr;
  unsigned short* negh = (unsigned short*)(scr + 4194304);
  unsigned short* At2  = (unsigned short*)(scr + 71303168);
  unsigned short* Bt2  = (unsigned short*)(scr + 121634816);

  // workspace: cadd (64 KiB) + idx array (256 KiB)
  float* cadd = (float*)d_ws;
  int*   idxa = (int*)((char*)d_ws + 65536);

  k_transA<<<BATCH * 64, 256, 0, stream>>>(z_p, At2);
  k_transB<<<BATCH * 16, 256, 0, stream>>>(m_p, logs_p, Bt2);
  k_cadd<<<(BATCH * TTXT) / 256, 256, 0, stream>>>(m_p, logs_p, cadd);
  k_mf<<<1024, 512, 0, stream>>>(At2, Bt2, cadd, neg, negh);
  k_dp<<<BATCH, 512, 0, stream>>>(negh, dur, idxa, x_mask, gbits);
  k_attn<<<(int)(ATTN_ELEMS / 4 / 256), 256, 0, stream>>>(idxa, x_mask, y_mask, attn);
}

// Round 22
// 500.130 us; speedup vs baseline: 1.4907x; 1.0338x over previous
//
#include <hip/hip_runtime.h>
#include <math.h>

// Problem constants (fixed by the reference setup_inputs)
#define BATCH 32
#define CH    192
#define TFEAT 2048
#define TTXT  512
#define NEGINF (-1e9f)

#define ATTN_ELEMS ((size_t)BATCH * TFEAT * TTXT)   // 33,554,432
#define DUR_OFF    ATTN_ELEMS
#define NEG_OFF    (ATTN_ELEMS + (size_t)BATCH * TTXT)

typedef short bf16x8 __attribute__((ext_vector_type(8)));   // 8 bf16 = 4 VGPR
typedef float f32x16 __attribute__((ext_vector_type(16)));  // 32x32 acc

__device__ __forceinline__ void gload_lds16h(const unsigned short* g,
                                             unsigned short* l) {
  __builtin_amdgcn_global_load_lds(
      (const __attribute__((address_space(1))) void*)g,
      (__attribute__((address_space(3))) void*)l, 16, 0, 0);
}

#define VMCNT(n) asm volatile("s_waitcnt vmcnt(" #n ")" ::: "memory")

__device__ __forceinline__ unsigned short f2b16(float f) {   // RNE bf16
  unsigned u = __float_as_uint(f);
  return (unsigned short)((u + 0x7FFFu + ((u >> 16) & 1u)) >> 16);
}

// ---------------------------------------------------------------------------
// Kernel TA: At2 = fragment-ready bf16 of A = [z | z^2] (M=2048, K=384).
// ---------------------------------------------------------------------------
__global__ __launch_bounds__(256)
void k_transA(const float* __restrict__ z_p, unsigned short* __restrict__ At2) {
  __shared__ float zt[CH][33];
  int b = blockIdx.x >> 6, tblk = blockIdx.x & 63;
  int tid = threadIdx.x;
  int t0 = tblk * 32;
  for (int i = tid; i < CH * 32; i += 256) {
    int c = i >> 5, m = i & 31;
    zt[c][m] = z_p[((size_t)b * CH + c) * TFEAT + t0 + m];
  }
  __syncthreads();
  unsigned short* out = At2 + (size_t)(b * 64 + tblk) * 24 * 512;
  for (int o = tid; o < 24 * 512; o += 256) {
    int kq = o >> 9, rem = o & 511;
    int lane = rem >> 3, j = rem & 7;
    int m = lane & 31, kh = lane >> 5;
    int k = kq * 16 + kh * 8 + j;
    float f;
    if (k < CH) f = zt[k][m];
    else { float z = zt[k - CH][m]; f = z * z; }
    out[o] = f2b16(f);
  }
}

// ---------------------------------------------------------------------------
// Kernel TB: Bt2 = fragment-ready bf16 of B = [W1 ; W2] (K=384, N=512).
// ---------------------------------------------------------------------------
__global__ __launch_bounds__(256)
void k_transB(const float* __restrict__ m_p, const float* __restrict__ logs_p,
              unsigned short* __restrict__ Bt2) {
  __shared__ float w1t[CH][33];
  __shared__ float w2t[CH][33];
  int b = blockIdx.x >> 4, sblk = blockIdx.x & 15;
  int tid = threadIdx.x;
  int s0 = sblk * 32;
  for (int i = tid; i < CH * 32; i += 256) {
    int c = i >> 5, n = i & 31;
    size_t idx = ((size_t)b * CH + c) * TTXT + s0 + n;
    float m = m_p[idx];
    float r = __expf(-2.0f * logs_p[idx]);
    w1t[c][n] = m * r;
    w2t[c][n] = -0.5f * r;
  }
  __syncthreads();
  unsigned short* out = Bt2 + (size_t)(b * 16 + sblk) * 24 * 512;
  for (int o = tid; o < 24 * 512; o += 256) {
    int kq = o >> 9, rem = o & 511;
    int lane = rem >> 3, j = rem & 7;
    int n = lane & 31, kh = lane >> 5;
    int k = kq * 16 + kh * 8 + j;
    float f = (k < CH) ? w1t[k][n] : w2t[k - CH][n];
    out[o] = f2b16(f);
  }
}

// ---------------------------------------------------------------------------
// Kernel A: cadd[b][s] = sum_c(-0.5*log(2pi) - logs) + sum_c(-0.5*m^2*r)
// ---------------------------------------------------------------------------
__global__ void k_cadd(const float* __restrict__ m_p,
                       const float* __restrict__ logs_p,
                       float* __restrict__ cadd) {
  int gid = blockIdx.x * 256 + threadIdx.x;        // 0 .. 16383
  int b = gid >> 9, s = gid & (TTXT - 1);
  const float* mp = m_p    + (size_t)b * CH * TTXT + s;
  const float* lp = logs_p + (size_t)b * CH * TTXT + s;
  float acc = -0.5f * 1.8378770664093453f * (float)CH;   // -C/2 * log(2*pi)
  #pragma unroll 4
  for (int c = 0; c < CH; ++c) {
    float l = lp[(size_t)c * TTXT];
    float m = mp[(size_t)c * TTXT];
    float r = __expf(-2.0f * l);
    acc -= l + 0.5f * m * m * r;
  }
  cadd[gid] = acc;
}

// ---------------------------------------------------------------------------
// Kernel B: bf16 MFMA GEMM (R19, UNCHANGED).
// ---------------------------------------------------------------------------
__global__ __launch_bounds__(512)
void k_mf(const unsigned short* __restrict__ At2,
          const unsigned short* __restrict__ Bt2,
          const float* __restrict__ cadd,
          float* __restrict__ neg,
          unsigned short* __restrict__ negh) {
  int blk = (blockIdx.x & 7) * 128 + (blockIdx.x >> 3);
  int sb = blk & 1;            // 512/256 = 2 col-blocks
  int tb = (blk >> 1) & 15;    // 2048/128 = 16 row-blocks
  int b  = blk >> 5;
  int tid = threadIdx.x, lane = tid & 63, w = tid >> 6;
  int rg = w >> 2, cg = w & 3;
  int trow0 = tb * 128 + rg * 64;
  int scol0 = sb * 256 + cg * 64;

  const unsigned short* ap0 = At2 + ((size_t)(b * 64 + (trow0 >> 5)) * 24) * 512 + lane * 8;
  const unsigned short* ap1 = ap0 + (size_t)24 * 512;
  const unsigned short* bp0 = Bt2 + ((size_t)(b * 16 + (scol0 >> 5)) * 24) * 512 + lane * 8;
  const unsigned short* bp1 = bp0 + (size_t)24 * 512;

  f32x16 acc00, acc01, acc10, acc11;
  #pragma unroll
  for (int r = 0; r < 16; ++r) { acc00[r] = 0.f; acc01[r] = 0.f; acc10[r] = 0.f; acc11[r] = 0.f; }

  bf16x8 a0A, a1A, b0A, b1A;
  bf16x8 a0B, a1B, b0B, b1B;

  auto LDA = [&](bf16x8& x0, bf16x8& x1, bf16x8& y0, bf16x8& y1, int kq) {
    x0 = *(const bf16x8*)(ap0 + (size_t)kq * 512);
    x1 = *(const bf16x8*)(ap1 + (size_t)kq * 512);
    y0 = *(const bf16x8*)(bp0 + (size_t)kq * 512);
    y1 = *(const bf16x8*)(bp1 + (size_t)kq * 512);
  };
  auto FMA = [&](bf16x8& x0, bf16x8& x1, bf16x8& y0, bf16x8& y1) {
    acc00 = __builtin_amdgcn_mfma_f32_32x32x16_bf16(x0, y0, acc00, 0, 0, 0);
    acc01 = __builtin_amdgcn_mfma_f32_32x32x16_bf16(x0, y1, acc01, 0, 0, 0);
    acc10 = __builtin_amdgcn_mfma_f32_32x32x16_bf16(x1, y0, acc10, 0, 0, 0);
    acc11 = __builtin_amdgcn_mfma_f32_32x32x16_bf16(x1, y1, acc11, 0, 0, 0);
  };

  LDA(a0A, a1A, b0A, b1A, 0);
  #pragma unroll
  for (int kq = 0; kq < 24; kq += 2) {
    LDA(a0B, a1B, b0B, b1B, kq + 1);
    FMA(a0A, a1A, b0A, b1A);
    __builtin_amdgcn_sched_barrier(0);
    if (kq + 2 < 24) LDA(a0A, a1A, b0A, b1A, kq + 2);
    FMA(a0B, a1B, b0B, b1B);
    __builtin_amdgcn_sched_barrier(0);
  }

  #pragma unroll
  for (int ti = 0; ti < 2; ++ti) {
    #pragma unroll
    for (int tj = 0; tj < 2; ++tj) {
      const f32x16& v = (ti == 0) ? ((tj == 0) ? acc00 : acc01)
                                  : ((tj == 0) ? acc10 : acc11);
      int s = scol0 + tj * 32 + (lane & 31);
      float cv = cadd[b * TTXT + s];
      int tB = trow0 + ti * 32 + 4 * (lane >> 5);
      float* np_ = neg + (size_t)b * TFEAT * TTXT + s;
      #pragma unroll
      for (int r = 0; r < 16; ++r) {
        int t = tB + (r & 3) + 8 * (r >> 2);
        float o = v[r] + cv;
        np_[(size_t)t * TTXT] = o;
        negh[(((size_t)b * 128 + (t >> 4)) * 8 + (s >> 6)) * 1024
             + (t & 15) * 64 + (s & 63)] = f2b16(o);
      }
    }
  }
}

// ---------------------------------------------------------------------------
// Kernel C (R22): skewed-wavefront DP = R21 EXCEPT the row body's cross-lane
// diet: readlane(prev,63)+mine-select bkeep (3 ops/row + VALU->SGPR hazards)
// replaced by bnd_hist[r]=prev (1 v_mov, static idx) + one per-window
// lane==63 block writing 4x ds_write_b128 to bndlds (same values -> bit-
// exact). T5 setprio(1) wraps the row chain. Ballot/keeps/u64 backtrack and
// the R21 store-aware vmcnt schedule unchanged.
// Pre-commit: >=340us => per-row cost is sync/latency-intrinsic; declare
// k_dp's structural floor.
// ---------------------------------------------------------------------------
#define KROWS 16
#define NWIN  (TFEAT / KROWS)     // 128 windows
#define NMASKW (TTXT / KROWS)     // 32 masked windows

__device__ __forceinline__ float dpp_shr1(float v) {
  return __int_as_float(__builtin_amdgcn_update_dpp(
      __float_as_int(v), __float_as_int(v), 0x138 /*wave_shr:1*/, 0xF, 0xF, false));
}

__global__ __launch_bounds__(512, 1)
void k_dp(const unsigned short* __restrict__ negh, float* __restrict__ dur,
          int* __restrict__ idx_out, const float* __restrict__ x_mask,
          unsigned long long* __restrict__ gbits_all) {
  __shared__ unsigned short ringh[8][4][KROWS * 64];  // 65536 B per-wave ring
  __shared__ float bndlds[3][8][KROWS];               //  1536 B boundary ring
  int b = blockIdx.x, tid = threadIdx.x;
  int lane = tid & 63, w = tid >> 6;
  // wave w's slice stream: blocks of 1024 ushorts per (window, wave)
  const unsigned short* nb =
      negh + (((size_t)b * NWIN) * 8 + w) * 1024 + lane * 8;
  unsigned long long* gbits = gbits_all + (size_t)b * 8 * TFEAT;  // [8][2048]

  if (tid < 3 * 8 * KROWS) ((float*)bndlds)[tid] = NEGINF;

  auto stage = [&](int j) {               // 2 contiguous 1KB loads
    int slot = j & 3;
    const unsigned short* s0 = nb + (size_t)j * 8 * 1024;
    gload_lds16h(s0,       &ringh[w][slot][0]);
    gload_lds16h(s0 + 512, &ringh[w][slot][512]);
  };

  stage(0); stage(1); stage(2);
  __syncthreads();                        // drains prologue loads + bndlds init

  float prev = NEGINF;
  for (int p = 0; p < NWIN + 8; ++p) {
    int i = p - w;                        // this wave's window this phase
    if (i >= 0 && i + 3 < NWIN) {
      stage(i + 3);
      // store-aware wait (R21): window i's loads done without draining
      // newer stores (2*min(3,rem) loads + min(i,3) stores after them)
      if (i >= 3)      VMCNT(9);
      else if (i == 2) VMCNT(8);
      else if (i == 1) VMCNT(7);
      else             VMCNT(6);          // i == 0
    } else if (i >= 0) {
      int rem = NWIN - 1 - i;
      if (rem == 2)      VMCNT(7);
      else if (rem == 1) VMCNT(5);
      else               VMCNT(3);
    }
    asm volatile("s_waitcnt lgkmcnt(0)" ::: "memory");
    __builtin_amdgcn_s_barrier();         // bndlds(prev phase) visible
    __builtin_amdgcn_sched_barrier(0);

    if (i >= 0 && i < NWIN) {
      // hoisted boundary values (wave-uniform)
      float s_bnd[KROWS];
      if (w > 0) {
        float v   = bndlds[i % 3][w - 1][lane & 15];
        float v15 = bndlds[(i + 2) % 3][w - 1][15];
        s_bnd[0] = __int_as_float(__builtin_amdgcn_readfirstlane(__float_as_int(v15)));
        #pragma unroll
        for (int r = 1; r < KROWS; ++r)
          s_bnd[r] = __int_as_float(__builtin_amdgcn_readlane(__float_as_int(v), r - 1));
      } else {
        #pragma unroll
        for (int r = 0; r < KROWS; ++r) s_bnd[r] = NEGINF;
        if (i == 0) s_bnd[0] = 0.0f;      // y==0, x==0 edge
      }
      // own-slice nf: bf16 -> f32 exact decode
      float cur[KROWS];
      #pragma unroll
      for (int r = 0; r < KROWS; ++r)
        cur[r] = __uint_as_float((unsigned)ringh[w][i & 3][r * 64 + lane] << 16);

      int y0 = i * KROWS;
      bool masked = (i < NMASKW);
      unsigned keep_lo = 0, keep_hi = 0;
      float bnd_hist[KROWS];              // lane63's copy feeds bndlds
      unsigned long long andm = (w == 0) ? ~1ull : ~0ull;   // x==0 never moves
      __builtin_amdgcn_s_setprio(1);
      #pragma unroll
      for (int r = 0; r < KROWS; ++r) {
        float upd = dpp_shr1(prev);
        float up = (lane == 0) ? s_bnd[r] : upd;
        bool force = masked && (tid == y0 + r);
        bool gt = prev < up;
        unsigned long long m = __ballot(force || gt) & andm;  // uniform
        bool mine = (lane == r);
        keep_lo = mine ? (unsigned)m : keep_lo;
        keep_hi = mine ? (unsigned)(m >> 32) : keep_hi;
        float vc = force ? NEGINF : prev;
        prev = fmaxf(vc, up) + cur[r];
        bnd_hist[r] = prev;               // static index, 1 v_mov
      }
      __builtin_amdgcn_s_setprio(0);
      if (lane == 63) {                   // boundary handoff, 4x b128
        float4* bd = (float4*)&bndlds[i % 3][w][0];
        bd[0] = make_float4(bnd_hist[0],  bnd_hist[1],  bnd_hist[2],  bnd_hist[3]);
        bd[1] = make_float4(bnd_hist[4],  bnd_hist[5],  bnd_hist[6],  bnd_hist[7]);
        bd[2] = make_float4(bnd_hist[8],  bnd_hist[9],  bnd_hist[10], bnd_hist[11]);
        bd[3] = make_float4(bnd_hist[12], bnd_hist[13], bnd_hist[14], bnd_hist[15]);
      }
      if (lane < KROWS) {                 // decision bits
        gbits[(size_t)w * TFEAT + y0 + lane] =
            ((unsigned long long)keep_hi << 32) | keep_lo;   // 128B contiguous
      }
    }
  }
  VMCNT(0);
  __syncthreads();                        // gbits stores drained + visible

  // ---- serial backtrack (tid 0), 16-deep register ring over global bits.
  if (tid == 0) {
    const float* xm = x_mask + (size_t)b * TTXT;
    int idx = TTXT - 1, cnt = 0;
    unsigned long long ua[16], ub[16]; int qi[16];
    #pragma unroll
    for (int q16 = 0; q16 < 16; ++q16) {  // rows 2032..2047 (slot = y&15)
      ua[q16] = gbits[(size_t)7 * TFEAT + 2032 + q16];
      ub[q16] = gbits[(size_t)6 * TFEAT + 2032 + q16];
      qi[q16] = 7;
    }
    for (int yb = 2032; yb >= 16; yb -= 16) {
      #pragma unroll
      for (int jj = 15; jj >= 0; --jj) {
        int y = yb + jj;                  // slot = jj (yb % 16 == 0)
        unsigned long long w64 = ((idx >> 6) == qi[jj]) ? ua[jj] : ub[jj];
        idx_out[b * TFEAT + y] = idx;
        cnt++;
        if ((w64 >> (idx & 63)) & 1ull) {
          dur[b * TTXT + idx] = (float)cnt * xm[idx];
          cnt = 0; idx--;
        }
        int q = idx >> 6;                 // refill slot jj for row y-16
        int qm = q > 0 ? q - 1 : 0;
        ua[jj] = gbits[(size_t)q  * TFEAT + (y - 16)];
        ub[jj] = gbits[(size_t)qm * TFEAT + (y - 16)];
        qi[jj] = q;
      }
    }
    #pragma unroll
    for (int jj = 15; jj >= 0; --jj) {    // tail rows 15..0
      int y = jj;
      unsigned long long w64 = ((idx >> 6) == qi[jj]) ? ua[jj] : ub[jj];
      idx_out[b * TFEAT + y] = idx;
      cnt++;
      if ((w64 >> (idx & 63)) & 1ull) {
        dur[b * TTXT + idx] = (float)cnt * xm[idx];
        cnt = 0; idx--;
      }
    }
    dur[b * TTXT] = (float)cnt * xm[0];   // idx == 0 tail run
  }
}

// ---------------------------------------------------------------------------
// Kernel D: attn[b,y,x] = (x == idx[y]) * x_mask[b,x] * y_mask[b,y]
// ---------------------------------------------------------------------------
__global__ void k_attn(const int* __restrict__ idx_arr,
                       const float* __restrict__ x_mask,
                       const float* __restrict__ y_mask,
                       float* __restrict__ attn) {
  size_t gid = (size_t)blockIdx.x * 256 + threadIdx.x;
  size_t e = gid << 2;               // 4 floats per thread
  int b = (int)(e >> 20);            // TFEAT*TTXT = 2^20
  int rem = (int)(e & 1048575u);
  int y = rem >> 9;
  int x0 = rem & 511;
  int idx = idx_arr[b * TFEAT + y];
  float4 v = {0.f, 0.f, 0.f, 0.f};
  int d = idx - x0;
  if (d >= 0 && d < 4) {
    ((float*)&v)[d] = x_mask[b * TTXT + idx] * y_mask[b * TFEAT + y];
  }
  *(float4*)(attn + e) = v;
}

// ---------------------------------------------------------------------------
extern "C" void kernel_launch(void* const* d_in, const int* in_sizes, int n_in,
                              void* d_out, int out_size, void* d_ws, size_t ws_size,
                              hipStream_t stream) {
  const float* z_p    = (const float*)d_in[0];
  const float* m_p    = (const float*)d_in[1];
  const float* logs_p = (const float*)d_in[2];
  const float* x_mask = (const float*)d_in[3];
  const float* y_mask = (const float*)d_in[4];

  float* out  = (float*)d_out;
  float* attn = out;
  float* dur  = out + DUR_OFF;
  float* neg  = out + NEG_OFF;

  // scratch in the attn region (134,217,728 B; fully rewritten by k_attn):
  //   gbits 4MB | negh 64MB | At2 48MB | Bt2 12MB  (exact fit)
  char* scr = (char*)attn;
  unsigned long long* gbits = (unsigned long long*)scr;
  unsigned short* negh = (unsigned short*)(scr + 4194304);
  unsigned short* At2  = (unsigned short*)(scr + 71303168);
  unsigned short* Bt2  = (unsigned short*)(scr + 121634816);

  // workspace: cadd (64 KiB) + idx array (256 KiB)
  float* cadd = (float*)d_ws;
  int*   idxa = (int*)((char*)d_ws + 65536);

  k_transA<<<BATCH * 64, 256, 0, stream>>>(z_p, At2);
  k_transB<<<BATCH * 16, 256, 0, stream>>>(m_p, logs_p, Bt2);
  k_cadd<<<(BATCH * TTXT) / 256, 256, 0, stream>>>(m_p, logs_p, cadd);
  k_mf<<<1024, 512, 0, stream>>>(At2, Bt2, cadd, neg, negh);
  k_dp<<<BATCH, 512, 0, stream>>>(negh, dur, idxa, x_mask, gbits);
  k_attn<<<(int)(ATTN_ELEMS / 4 / 256), 256, 0, stream>>>(idxa, x_mask, y_mask, attn);
}